// Round 6
// baseline (203.422 us; speedup 1.0000x reference)
//
#include <hip/hip_runtime.h>
#include <cstdint>

typedef __attribute__((ext_vector_type(8))) short short8;
typedef __attribute__((ext_vector_type(8))) unsigned short ushort8;
typedef __attribute__((ext_vector_type(4))) unsigned short ushort4v;
typedef __attribute__((ext_vector_type(4))) float f32x4;

constexpr int NB = 256, MC = 128, MP = 256;
constexpr float L2E = 1.442695041f;

__device__ __forceinline__ float b2f(unsigned short h) { return __uint_as_float(((unsigned)h) << 16); }
__device__ __forceinline__ unsigned short f2b(float f) {
    unsigned u = __float_as_uint(f);
    u += 0x7fffu + ((u >> 16) & 1u);
    return (unsigned short)(u >> 16);
}
__device__ __forceinline__ float sigmoid_f(float x) {
    return __builtin_amdgcn_rcpf(1.f + exp2f(-L2E * x));
}
__device__ __forceinline__ void gld_lds16(const unsigned short* g, unsigned short* l) {
    __builtin_amdgcn_global_load_lds((const __attribute__((address_space(1))) void*)g,
                                     (__attribute__((address_space(3))) void*)l, 16, 0, 0);
}

__global__ __launch_bounds__(256)
void cvt_f32_bf16(const float* __restrict__ in, unsigned short* __restrict__ out, int n4) {
    int i = blockIdx.x * 256 + threadIdx.x;
    int stride = gridDim.x * 256;
    for (; i < n4; i += stride) {
        float4 v = ((const float4*)in)[i];
        ushort4v o;
        o.x = f2b(v.x); o.y = f2b(v.y); o.z = f2b(v.z); o.w = f2b(v.w);
        ((ushort4v*)out)[i] = o;
    }
}

// 8 weights -> Wcat [2048][256] bf16 + bias_cat[2048] f32.
// Row-block order: q_c,k_c,v_c,g_c,q_p,k_p,v_p,g_p (qkv contiguous per side).
__global__ __launch_bounds__(256)
void cvt_weights8(const float* w0, const float* w1, const float* w2, const float* w3,
                  const float* w4, const float* w5, const float* w6, const float* w7,
                  const float* b0, const float* b1, const float* b2, const float* b3,
                  const float* b4, const float* b5, const float* b6, const float* b7,
                  unsigned short* __restrict__ Wcat, float* __restrict__ bias_cat)
{
    const float* wsel[8] = {w0, w1, w2, w3, w4, w5, w6, w7};
    const float* bsel[8] = {b0, b1, b2, b3, b4, b5, b6, b7};
    int j = blockIdx.y;
    int i = blockIdx.x * 256 + threadIdx.x;
    float4 v = ((const float4*)wsel[j])[i];
    ushort4v o;
    o.x = f2b(v.x); o.y = f2b(v.y); o.z = f2b(v.z); o.w = f2b(v.w);
    ((ushort4v*)(Wcat + (size_t)j * 65536))[i] = o;
    if (blockIdx.x == 0) bias_cat[j * 256 + threadIdx.x] = bsel[j][threadIdx.x];
}

// ---------------------------------------------------------------------------
// bf16 MFMA GEMM, double-buffered BK=32 (2-phase pipeline).
// LDS: elem (row r,k) at short-index r*32 + ((k>>3 ^ (r&3))<<3) + (k&7);
// staged linearly from inverse-swizzled GLOBAL source (rule #21).
// MODE 0 proj : Y[gr,gc] = dot + bias[gc], C stride N (N=768 fused qkv)
// MODE 2 AV   : O = Attn . V[gather]  (V rows via bidx, stride bstr)
// MODE 3 gate : C = C * sigmoid(dot + bias), in place (block owns full rows)
// ---------------------------------------------------------------------------
template<int MODE>
__global__ __launch_bounds__(256, 4)
void mfma_gemm(const unsigned short* __restrict__ A, const unsigned short* __restrict__ B,
               unsigned short* __restrict__ C, const float* __restrict__ bias,
               const int* __restrict__ aidx, const int* __restrict__ bidx,
               int M, int N, int K, int bstr)
{
    constexpr int BM = (MODE == 3) ? 64 : 128;
    constexpr int BN = (MODE == 3) ? 256 : 128;
    __shared__ __align__(16) unsigned short As[2][BM * 32];
    __shared__ __align__(16) unsigned short Bs[2][BN * 32];

    const int t = threadIdx.x;
    const int wid = t >> 6, l = t & 63, g = l >> 4, lr = l & 15;
    const int wrb = (MODE == 3) ? 0 : (wid >> 1) * 64;
    const int wcb = (MODE == 3) ? wid * 64 : (wid & 1) * 64;
    const int r0 = blockIdx.x * BM, c0 = blockIdx.y * BN;
    const int bz = blockIdx.z;

    f32x4 acc[4][4];
#pragma unroll
    for (int mi = 0; mi < 4; ++mi)
#pragma unroll
        for (int ni = 0; ni < 4; ++ni) acc[mi][ni] = (f32x4){0.f, 0.f, 0.f, 0.f};

    auto stage = [&](int buf, int k0) {
        constexpr int CA = (BM * 4) / 256;
#pragma unroll
        for (int p = 0; p < CA; ++p) {
            int i = p * 256 + t;
            int r = i >> 2, s = i & 3;
            const unsigned short* ap;
            if constexpr (MODE == 0) { int gr = r0 + r; if (gr >= M) gr = M - 1; ap = A + (size_t)gr * 256; }
            else if constexpr (MODE == 2) { ap = A + ((size_t)bz * M + r0 + r) * K; }
            else { ap = A + (size_t)(r0 + r) * 256; }
            gld_lds16(ap + k0 + ((s ^ (r & 3)) << 3), &As[buf][i * 8]);
        }
        if constexpr (MODE == 2) {
            int a = t & 15, cb = (t >> 4) * 8;
            const unsigned short* q0 = B + (size_t)bidx[bz * K + k0 + 2 * a] * bstr + c0 + cb;
            const unsigned short* q1 = B + (size_t)bidx[bz * K + k0 + 2 * a + 1] * bstr + c0 + cb;
            ushort8 v0 = *(const ushort8*)q0;
            ushort8 v1 = *(const ushort8*)q1;
            int gg = a >> 2, kl = (2 * a) & 7;
#pragma unroll
            for (int e = 0; e < 8; ++e) {
                int c = cb + e;
                *(unsigned*)&Bs[buf][c * 32 + ((gg ^ (c & 3)) << 3) + kl] =
                    (unsigned)(unsigned short)v0[e] | ((unsigned)(unsigned short)v1[e] << 16);
            }
        } else {
            constexpr int CB = (BN * 4) / 256;
#pragma unroll
            for (int p = 0; p < CB; ++p) {
                int i = p * 256 + t;
                int c = i >> 2, s = i & 3;
                const unsigned short* bp = B + (size_t)(c0 + c) * bstr;
                gld_lds16(bp + k0 + ((s ^ (c & 3)) << 3), &Bs[buf][i * 8]);
            }
        }
    };

    stage(0, 0);
    __syncthreads();
    const int NT_ = K >> 5;
    for (int it = 0; it < NT_; ++it) {
        const int cur = it & 1;
        if (it + 1 < NT_) stage(cur ^ 1, (it + 1) << 5);
        short8 af[4], bfr[4];
#pragma unroll
        for (int mi = 0; mi < 4; ++mi) {
            int r = wrb + mi * 16 + lr;
            af[mi] = *(const short8*)&As[cur][r * 32 + ((g ^ (r & 3)) << 3)];
        }
#pragma unroll
        for (int ni = 0; ni < 4; ++ni) {
            int c = wcb + ni * 16 + lr;
            bfr[ni] = *(const short8*)&Bs[cur][c * 32 + ((g ^ (c & 3)) << 3)];
        }
#pragma unroll
        for (int mi = 0; mi < 4; ++mi)
#pragma unroll
            for (int ni = 0; ni < 4; ++ni)
                acc[mi][ni] = __builtin_amdgcn_mfma_f32_16x16x32_bf16(af[mi], bfr[ni], acc[mi][ni], 0, 0, 0);
        if (it + 1 < NT_) __syncthreads();
    }

#pragma unroll
    for (int mi = 0; mi < 4; ++mi) {
#pragma unroll
        for (int ni = 0; ni < 4; ++ni) {
#pragma unroll
            for (int q = 0; q < 4; ++q) {
                int gr = r0 + wrb + mi * 16 + g * 4 + q;
                int gc = c0 + wcb + ni * 16 + lr;
                float v = acc[mi][ni][q];
                if constexpr (MODE == 0) {
                    if (gr < M) C[(size_t)gr * N + gc] = f2b(v + bias[gc]);
                } else if constexpr (MODE == 2) {
                    C[((size_t)bz * M + gr) * 256 + gc] = f2b(v);
                } else {
                    size_t o = (size_t)gr * 256 + gc;
                    C[o] = f2b(b2f(C[o]) * sigmoid_f(v + bias[gc]));
                }
            }
        }
    }
}

// ---------------------------------------------------------------------------
// Fused masked-score + softmax + importance, ROW-SPLIT version.
// grid = (Mfull/MB, NB); block = 256 thr = 4 waves in WR x WC (WR*WC=4),
// block computes rows [rbase, rbase+MB) x ALL NN cols (row softmax local).
// Row pointers (swizzle pre-folded) hoisted into registers before k-loop.
// IMP: imp_c[row] = 1/rowsum; imp_p_part[rowblk][bz][col] = partial col-max
// over this block's valid rows (merged in pool_kernel).
// ---------------------------------------------------------------------------
template<int MB, int NN, int WR, int WC, bool IMP>
__global__ __launch_bounds__(256, 3)
void attn_score(const unsigned short* __restrict__ Aq, const unsigned short* __restrict__ Bk,
                unsigned short* __restrict__ S,
                const int* __restrict__ aidx, const int* __restrict__ bidx,
                const int* __restrict__ rlen, const int* __restrict__ cln,
                float* __restrict__ imp_c, float* __restrict__ imp_p_part, int Mfull)
{
    __shared__ __align__(16) unsigned short As[2][MB * 32];
    __shared__ __align__(16) unsigned short Bs[2][NN * 32];
    __shared__ float redA[MB][WC + 1];

    const int t = threadIdx.x;
    const int wid = t >> 6, l = t & 63, g = l >> 4, lr = l & 15;
    const int wr = wid / WC, wc = wid % WC;
    const int R0 = wr * 64, C0 = wc * 64;
    const int rbase = blockIdx.x * MB;
    const int bz = blockIdx.y;
    const int rl = rlen[bz], cl_ = cln[bz];

    // hoisted, swizzle-folded row pointers
    constexpr int CA = (MB * 4) / 256, CB = (NN * 4) / 256;
    const unsigned short* apr[CA];
    const unsigned short* bpr[CB];
#pragma unroll
    for (int p = 0; p < CA; ++p) {
        int i = p * 256 + t, r = i >> 2, s = i & 3;
        apr[p] = Aq + (size_t)aidx[bz * Mfull + rbase + r] * 768 + ((s ^ (r & 3)) << 3);
    }
#pragma unroll
    for (int p = 0; p < CB; ++p) {
        int i = p * 256 + t, c = i >> 2, s = i & 3;
        bpr[p] = Bk + (size_t)bidx[bz * NN + c] * 768 + ((s ^ (c & 3)) << 3);
    }

    f32x4 acc[4][4];
#pragma unroll
    for (int mi = 0; mi < 4; ++mi)
#pragma unroll
        for (int ni = 0; ni < 4; ++ni) acc[mi][ni] = (f32x4){0.f, 0.f, 0.f, 0.f};

    auto stage = [&](int buf, int k0) {
#pragma unroll
        for (int p = 0; p < CA; ++p) gld_lds16(apr[p] + k0, &As[buf][(p * 256 + t) * 8]);
#pragma unroll
        for (int p = 0; p < CB; ++p) gld_lds16(bpr[p] + k0, &Bs[buf][(p * 256 + t) * 8]);
    };

    stage(0, 0);
    __syncthreads();
#pragma unroll 2
    for (int it = 0; it < 8; ++it) {
        const int cur = it & 1;
        if (it + 1 < 8) stage(cur ^ 1, (it + 1) << 5);
        short8 af[4], bfr[4];
#pragma unroll
        for (int mi = 0; mi < 4; ++mi) {
            int r = R0 + mi * 16 + lr;
            af[mi] = *(const short8*)&As[cur][r * 32 + ((g ^ (r & 3)) << 3)];
        }
#pragma unroll
        for (int ni = 0; ni < 4; ++ni) {
            int c = C0 + ni * 16 + lr;
            bfr[ni] = *(const short8*)&Bs[cur][c * 32 + ((g ^ (c & 3)) << 3)];
        }
#pragma unroll
        for (int mi = 0; mi < 4; ++mi)
#pragma unroll
            for (int ni = 0; ni < 4; ++ni)
                acc[mi][ni] = __builtin_amdgcn_mfma_f32_16x16x32_bf16(af[mi], bfr[ni], acc[mi][ni], 0, 0, 0);
        if (it + 1 < 8) __syncthreads();
    }

    // ---- mask + scale (f32 scores) ----
#pragma unroll
    for (int mi = 0; mi < 4; ++mi)
#pragma unroll
        for (int ni = 0; ni < 4; ++ni)
#pragma unroll
            for (int q = 0; q < 4; ++q) {
                int grow = rbase + R0 + mi * 16 + g * 4 + q;
                int col = C0 + ni * 16 + lr;
                acc[mi][ni][q] = (grow < rl && col < cl_) ? acc[mi][ni][q] * 0.0625f : -1e9f;
            }

    // ---- row max ----
    float rm[4][4];
#pragma unroll
    for (int mi = 0; mi < 4; ++mi)
#pragma unroll
        for (int q = 0; q < 4; ++q) {
            float m = fmaxf(fmaxf(acc[mi][0][q], acc[mi][1][q]), fmaxf(acc[mi][2][q], acc[mi][3][q]));
#pragma unroll
            for (int o = 1; o < 16; o <<= 1) m = fmaxf(m, __shfl_xor(m, o));
            rm[mi][q] = m;
        }
    if (lr == 0)
#pragma unroll
        for (int mi = 0; mi < 4; ++mi)
#pragma unroll
            for (int q = 0; q < 4; ++q)
                redA[R0 + mi * 16 + g * 4 + q][wc] = rm[mi][q];
    __syncthreads();
    float Mrow[4][4];
#pragma unroll
    for (int mi = 0; mi < 4; ++mi)
#pragma unroll
        for (int q = 0; q < 4; ++q) {
            int row = R0 + mi * 16 + g * 4 + q;
            float m = redA[row][0];
#pragma unroll
            for (int w = 1; w < WC; ++w) m = fmaxf(m, redA[row][w]);
            Mrow[mi][q] = m;
        }
    __syncthreads();

    // ---- exp + row sum ----
#pragma unroll
    for (int mi = 0; mi < 4; ++mi)
#pragma unroll
        for (int q = 0; q < 4; ++q) {
            float s = 0.f;
#pragma unroll
            for (int ni = 0; ni < 4; ++ni) {
                float e = exp2f((acc[mi][ni][q] - Mrow[mi][q]) * L2E);
                acc[mi][ni][q] = e;
                s += e;
            }
#pragma unroll
            for (int o = 1; o < 16; o <<= 1) s += __shfl_xor(s, o);
            rm[mi][q] = s;
        }
    if (lr == 0)
#pragma unroll
        for (int mi = 0; mi < 4; ++mi)
#pragma unroll
            for (int q = 0; q < 4; ++q)
                redA[R0 + mi * 16 + g * 4 + q][wc] = rm[mi][q];
    __syncthreads();
    float inv[4][4];
#pragma unroll
    for (int mi = 0; mi < 4; ++mi)
#pragma unroll
        for (int q = 0; q < 4; ++q) {
            int row = R0 + mi * 16 + g * 4 + q;
            float s = redA[row][0];
#pragma unroll
            for (int w = 1; w < WC; ++w) s += redA[row][w];
            inv[mi][q] = 1.f / s;
        }

    // ---- write normalized attn ----
#pragma unroll
    for (int mi = 0; mi < 4; ++mi)
#pragma unroll
        for (int ni = 0; ni < 4; ++ni)
#pragma unroll
            for (int q = 0; q < 4; ++q) {
                int grow = rbase + R0 + mi * 16 + g * 4 + q;
                int col = C0 + ni * 16 + lr;
                S[((size_t)bz * Mfull + grow) * NN + col] = f2b(acc[mi][ni][q] * inv[mi][q]);
            }

    if constexpr (IMP) {
        if (wc == 0 && lr == 0)
#pragma unroll
            for (int mi = 0; mi < 4; ++mi)
#pragma unroll
                for (int q = 0; q < 4; ++q)
                    imp_c[bz * Mfull + rbase + R0 + mi * 16 + g * 4 + q] = inv[mi][q];
        // partial col-max over this block's valid rows (WR==1)
        float cm[4];
#pragma unroll
        for (int ni = 0; ni < 4; ++ni) {
            float m = -1e30f;
#pragma unroll
            for (int mi = 0; mi < 4; ++mi)
#pragma unroll
                for (int q = 0; q < 4; ++q)
                    if (rbase + mi * 16 + g * 4 + q < rl)
                        m = fmaxf(m, acc[mi][ni][q] * inv[mi][q]);
            m = fmaxf(m, __shfl_xor(m, 16));
            m = fmaxf(m, __shfl_xor(m, 32));
            cm[ni] = m;
        }
        if (g == 0)
#pragma unroll
            for (int ni = 0; ni < 4; ++ni)
                imp_p_part[((size_t)blockIdx.x * NB + bz) * NN + C0 + ni * 16 + lr] = cm[ni];
    }
}

__device__ __forceinline__ float br_max(float v, float* red)
{
#pragma unroll
    for (int o = 32; o; o >>= 1) v = fmaxf(v, __shfl_xor(v, o));
    __syncthreads();
    if ((threadIdx.x & 63) == 0) red[threadIdx.x >> 6] = v;
    __syncthreads();
    return fmaxf(fmaxf(red[0], red[1]), fmaxf(red[2], red[3]));
}

__device__ __forceinline__ float br_sum(float v, float* red)
{
#pragma unroll
    for (int o = 32; o; o >>= 1) v += __shfl_xor(v, o);
    __syncthreads();
    if ((threadIdx.x & 63) == 0) red[threadIdx.x >> 6] = v;
    __syncthreads();
    return red[0] + red[1] + red[2] + red[3];
}

__global__ __launch_bounds__(256)
void pool_kernel(const unsigned short* __restrict__ cg, const unsigned short* __restrict__ pg,
                 const float* __restrict__ imp_c, const float* __restrict__ imp_p_part,
                 const int* __restrict__ clens, const int* __restrict__ plens,
                 float* __restrict__ out)
{
    int b = blockIdx.x, t = threadIdx.x;
    __shared__ float w[256];
    __shared__ float red[4];
    int cl = clens[b], pl = plens[b];

    float x = (t < 128 && t < cl) ? imp_c[b * MC + t] : -1e30f;
    float mx = br_max(x, red);
    float e = (t < 128) ? exp2f((x - mx) * L2E) : 0.f;
    float s = br_sum(e, red);
    if (t < 128) w[t] = e / s;
    __syncthreads();

    float hv = 0.f;
    for (int n = 0; n < MC; ++n)
        hv += w[n] * b2f(cg[((size_t)b * MC + n) * 256 + t]);
    __syncthreads();

    // merge the two row-block partials of imp_p
    float x2 = (t < pl) ? fmaxf(imp_p_part[(size_t)b * MP + t],
                                imp_p_part[(size_t)(NB + b) * MP + t]) : -1e30f;
    float mx2 = br_max(x2, red);
    float e2 = exp2f((x2 - mx2) * L2E);
    float s2 = br_sum(e2, red);
    w[t] = e2 / s2;
    __syncthreads();

    float dv = 0.f;
    for (int m = 0; m < MP; ++m)
        dv += w[m] * b2f(pg[((size_t)b * MP + m) * 256 + t]);

    float logit = br_sum(hv * dv, red);
    if (t == 0) out[b] = 1.f / (1.f + expf(-logit));
}

// ---------------------------------------------------------------------------
extern "C" void kernel_launch(void* const* d_in, const int* in_sizes, int n_in,
                              void* d_out, int out_size, void* d_ws, size_t ws_size,
                              hipStream_t stream)
{
    const float* comp_emb = (const float*)d_in[0];
    const float* prot_emb = (const float*)d_in[1];
    const int* comp_idx  = (const int*)d_in[18];
    const int* prot_idx  = (const int*)d_in[19];
    const int* comp_lens = (const int*)d_in[20];
    const int* prot_lens = (const int*)d_in[21];
    float* out = (float*)d_out;

    const int N_C = in_sizes[0] / 256;
    const int N_P = in_sizes[1] / 256;
    const size_t NTc = (size_t)N_C * 256;
    const size_t NTp = (size_t)N_P * 256;

    // ---- workspace layout (bf16 elems), ~168 MB of the 256 MiB ws ----
    unsigned short* comp_bf = (unsigned short*)d_ws;
    unsigned short* prot_bf = comp_bf + NTc;
    unsigned short* Wcat    = prot_bf + NTp;                 // [2048][256]
    float* bias_cat         = (float*)(Wcat + 2048 * 256);   // [2048]
    unsigned short* tabC    = (unsigned short*)(bias_cat + 2048);  // [N_C][768] q|k|v
    unsigned short* tabP    = tabC + (size_t)N_C * 768;            // [N_P][768] q|k|v
    unsigned short* S_cp    = tabP + (size_t)N_P * 768;      // [NB][128][256]
    unsigned short* S_pc    = S_cp + (size_t)NB * MC * MP;   // [NB][256][128]
    unsigned short* cfused  = S_pc + (size_t)NB * MP * MC;   // [NB][128][256]
    unsigned short* pfused  = cfused + (size_t)NB * MC * 256; // [NB][256][256]
    float* imp_c      = (float*)(pfused + (size_t)NB * MP * 256);
    float* imp_p_part = imp_c + NB * MC;                     // [2][NB][256]

    // ---- conversions ----
    cvt_f32_bf16<<<dim3(2048), 256, 0, stream>>>(comp_emb, comp_bf, (int)(NTc / 4));
    cvt_f32_bf16<<<dim3(2048), 256, 0, stream>>>(prot_emb, prot_bf, (int)(NTp / 4));
    cvt_weights8<<<dim3(64, 8), 256, 0, stream>>>(
        (const float*)d_in[2], (const float*)d_in[4], (const float*)d_in[6], (const float*)d_in[14],
        (const float*)d_in[8], (const float*)d_in[10], (const float*)d_in[12], (const float*)d_in[16],
        (const float*)d_in[3], (const float*)d_in[5], (const float*)d_in[7], (const float*)d_in[15],
        (const float*)d_in[9], (const float*)d_in[11], (const float*)d_in[13], (const float*)d_in[17],
        Wcat, bias_cat);

    const int gpc = (N_C + 127) / 128, gpp = (N_P + 127) / 128;

    // ---- fused qkv projections (one per side) ----
    mfma_gemm<0><<<dim3(gpc, 6, 1), 256, 0, stream>>>(comp_bf, Wcat, tabC, bias_cat,
        nullptr, nullptr, N_C, 768, 256, 256);
    mfma_gemm<0><<<dim3(gpp, 6, 1), 256, 0, stream>>>(prot_bf, Wcat + 1024 * 256, tabP, bias_cat + 1024,
        nullptr, nullptr, N_P, 768, 256, 256);

    // ---- fused score+softmax+imp, row-split ----
    attn_score<64, 256, 1, 4, true><<<dim3(2, NB), 256, 0, stream>>>(
        tabC, tabP + 256, S_cp, comp_idx, prot_idx, comp_lens, prot_lens, imp_c, imp_p_part, MC);
    attn_score<128, 128, 2, 2, false><<<dim3(2, NB), 256, 0, stream>>>(
        tabP, tabC + 256, S_pc, prot_idx, comp_idx, prot_lens, comp_lens, nullptr, nullptr, MP);

    // ---- attn @ V ----
    mfma_gemm<2><<<dim3(1, 2, NB), 256, 0, stream>>>(S_cp, tabP + 512, cfused, nullptr,
        nullptr, prot_idx, MC, 256, MP, 768);
    mfma_gemm<2><<<dim3(2, 2, NB), 256, 0, stream>>>(S_pc, tabC + 512, pfused, nullptr,
        nullptr, comp_idx, MP, 256, MC, 768);

    // ---- sigmoid gating (in place) ----
    mfma_gemm<3><<<dim3((NB * MC) / 64, 1, 1), 256, 0, stream>>>(cfused, Wcat + 768 * 256, cfused, bias_cat + 768,
        nullptr, nullptr, NB * MC, 256, 256, 256);
    mfma_gemm<3><<<dim3((NB * MP) / 64, 1, 1), 256, 0, stream>>>(pfused, Wcat + 1792 * 256, pfused, bias_cat + 1792,
        nullptr, nullptr, NB * MP, 256, 256, 256);

    // ---- pooling + logit ----
    pool_kernel<<<dim3(NB), 256, 0, stream>>>(cfused, pfused, imp_c, imp_p_part, comp_lens, prot_lens, out);
}

// Round 7
// 200.365 us; speedup vs baseline: 1.0153x; 1.0153x over previous
//
#include <hip/hip_runtime.h>
#include <cstdint>

typedef __attribute__((ext_vector_type(8))) short short8;
typedef __attribute__((ext_vector_type(8))) unsigned short ushort8;
typedef __attribute__((ext_vector_type(4))) unsigned short ushort4v;
typedef __attribute__((ext_vector_type(4))) float f32x4;

constexpr int NB = 256, MC = 128, MP = 256;
constexpr float L2E = 1.442695041f;

__device__ __forceinline__ float b2f(unsigned short h) { return __uint_as_float(((unsigned)h) << 16); }
__device__ __forceinline__ unsigned short f2b(float f) {
    unsigned u = __float_as_uint(f);
    u += 0x7fffu + ((u >> 16) & 1u);
    return (unsigned short)(u >> 16);
}
__device__ __forceinline__ float sigmoid_f(float x) {
    return __builtin_amdgcn_rcpf(1.f + exp2f(-L2E * x));
}
__device__ __forceinline__ void gld_lds16(const unsigned short* g, unsigned short* l) {
    __builtin_amdgcn_global_load_lds((const __attribute__((address_space(1))) void*)g,
                                     (__attribute__((address_space(3))) void*)l, 16, 0, 0);
}

__global__ __launch_bounds__(256)
void cvt_f32_bf16(const float* __restrict__ in, unsigned short* __restrict__ out, int n4) {
    int i = blockIdx.x * 256 + threadIdx.x;
    int stride = gridDim.x * 256;
    for (; i < n4; i += stride) {
        float4 v = ((const float4*)in)[i];
        ushort4v o;
        o.x = f2b(v.x); o.y = f2b(v.y); o.z = f2b(v.z); o.w = f2b(v.w);
        ((ushort4v*)out)[i] = o;
    }
}

// 8 weights -> Wcat [2048][256] bf16 + bias_cat[2048] f32.
// Row-block order: q_c,k_c,v_c,g_c,q_p,k_p,v_p,g_p (qkv contiguous per side).
__global__ __launch_bounds__(256)
void cvt_weights8(const float* w0, const float* w1, const float* w2, const float* w3,
                  const float* w4, const float* w5, const float* w6, const float* w7,
                  const float* b0, const float* b1, const float* b2, const float* b3,
                  const float* b4, const float* b5, const float* b6, const float* b7,
                  unsigned short* __restrict__ Wcat, float* __restrict__ bias_cat)
{
    const float* wsel[8] = {w0, w1, w2, w3, w4, w5, w6, w7};
    const float* bsel[8] = {b0, b1, b2, b3, b4, b5, b6, b7};
    int j = blockIdx.y;
    int i = blockIdx.x * 256 + threadIdx.x;
    float4 v = ((const float4*)wsel[j])[i];
    ushort4v o;
    o.x = f2b(v.x); o.y = f2b(v.y); o.z = f2b(v.z); o.w = f2b(v.w);
    ((ushort4v*)(Wcat + (size_t)j * 65536))[i] = o;
    if (blockIdx.x == 0) bias_cat[j * 256 + threadIdx.x] = bsel[j][threadIdx.x];
}

// ---------------------------------------------------------------------------
// bf16 MFMA GEMM, double-buffered BK=32 (2-phase pipeline).  (modes 0 & 3 used)
// LDS: elem (row r,k) at short-index r*32 + ((k>>3 ^ (r&3))<<3) + (k&7);
// staged linearly from inverse-swizzled GLOBAL source (rule #21).
// MODE 0 proj : Y[gr,gc] = dot + bias[gc], C stride N (N=768 fused qkv)
// MODE 3 gate : C = C * sigmoid(dot + bias), in place (block owns full rows)
// ---------------------------------------------------------------------------
template<int MODE>
__global__ __launch_bounds__(256, 4)
void mfma_gemm(const unsigned short* __restrict__ A, const unsigned short* __restrict__ B,
               unsigned short* __restrict__ C, const float* __restrict__ bias,
               int M, int N, int K, int bstr)
{
    constexpr int BM = (MODE == 3) ? 64 : 128;
    constexpr int BN = (MODE == 3) ? 256 : 128;
    __shared__ __align__(16) unsigned short As[2][BM * 32];
    __shared__ __align__(16) unsigned short Bs[2][BN * 32];

    const int t = threadIdx.x;
    const int wid = t >> 6, l = t & 63, g = l >> 4, lr = l & 15;
    const int wrb = (MODE == 3) ? 0 : (wid >> 1) * 64;
    const int wcb = (MODE == 3) ? wid * 64 : (wid & 1) * 64;
    const int r0 = blockIdx.x * BM, c0 = blockIdx.y * BN;

    f32x4 acc[4][4];
#pragma unroll
    for (int mi = 0; mi < 4; ++mi)
#pragma unroll
        for (int ni = 0; ni < 4; ++ni) acc[mi][ni] = (f32x4){0.f, 0.f, 0.f, 0.f};

    auto stage = [&](int buf, int k0) {
        constexpr int CA = (BM * 4) / 256;
#pragma unroll
        for (int p = 0; p < CA; ++p) {
            int i = p * 256 + t;
            int r = i >> 2, s = i & 3;
            const unsigned short* ap;
            if constexpr (MODE == 0) { int gr = r0 + r; if (gr >= M) gr = M - 1; ap = A + (size_t)gr * 256; }
            else { ap = A + (size_t)(r0 + r) * 256; }
            gld_lds16(ap + k0 + ((s ^ (r & 3)) << 3), &As[buf][i * 8]);
        }
        constexpr int CB = (BN * 4) / 256;
#pragma unroll
        for (int p = 0; p < CB; ++p) {
            int i = p * 256 + t;
            int c = i >> 2, s = i & 3;
            const unsigned short* bp = B + (size_t)(c0 + c) * bstr;
            gld_lds16(bp + k0 + ((s ^ (c & 3)) << 3), &Bs[buf][i * 8]);
        }
    };

    stage(0, 0);
    __syncthreads();
    const int NT_ = K >> 5;
    for (int it = 0; it < NT_; ++it) {
        const int cur = it & 1;
        if (it + 1 < NT_) stage(cur ^ 1, (it + 1) << 5);
        short8 af[4], bfr[4];
#pragma unroll
        for (int mi = 0; mi < 4; ++mi) {
            int r = wrb + mi * 16 + lr;
            af[mi] = *(const short8*)&As[cur][r * 32 + ((g ^ (r & 3)) << 3)];
        }
#pragma unroll
        for (int ni = 0; ni < 4; ++ni) {
            int c = wcb + ni * 16 + lr;
            bfr[ni] = *(const short8*)&Bs[cur][c * 32 + ((g ^ (c & 3)) << 3)];
        }
#pragma unroll
        for (int mi = 0; mi < 4; ++mi)
#pragma unroll
            for (int ni = 0; ni < 4; ++ni)
                acc[mi][ni] = __builtin_amdgcn_mfma_f32_16x16x32_bf16(af[mi], bfr[ni], acc[mi][ni], 0, 0, 0);
        if (it + 1 < NT_) __syncthreads();
    }

#pragma unroll
    for (int mi = 0; mi < 4; ++mi) {
#pragma unroll
        for (int ni = 0; ni < 4; ++ni) {
#pragma unroll
            for (int q = 0; q < 4; ++q) {
                int gr = r0 + wrb + mi * 16 + g * 4 + q;
                int gc = c0 + wcb + ni * 16 + lr;
                float v = acc[mi][ni][q];
                if constexpr (MODE == 0) {
                    if (gr < M) C[(size_t)gr * N + gc] = f2b(v + bias[gc]);
                } else {
                    size_t o = (size_t)gr * 256 + gc;
                    C[o] = f2b(b2f(C[o]) * sigmoid_f(v + bias[gc]));
                }
            }
        }
    }
}

// ---------------------------------------------------------------------------
// Mega-fused attention: QK^T (swapped operands) -> masked softmax (lane-local
// over kcols) -> P packed into LDS -> PV (swapped; V gathered+transposed,
// double-buffered, issue-early/write-late) -> packed fused-output stores.
// grid (Mfull/64, NB), 256 thr = 4 waves; wave owns kcol range in QK^T and
// dim range (wid*64..) in PV. Swapped layout: lane holds 4 consecutive kcols
// (QK) / 4 consecutive dims (PV) -> ushort4 packed writes.
// Ps swizzle: elem (row,kcol) -> slot=(kcol>>2)^((row&XM)<<3) (8B granular);
// write 4-pack and read b128 use the same map (slots pair-contiguous since
// XOR value has bit0=0).
// IMP: imp_c[row]=1/rowsum; imp_p_part[blk][bz][kcol]=col-max over valid rows.
// ---------------------------------------------------------------------------
template<int NN, bool IMP>
__global__ __launch_bounds__(256, 2)
void attn_fused(const unsigned short* __restrict__ Qt, const unsigned short* __restrict__ Kt,
                const unsigned short* __restrict__ Vt, unsigned short* __restrict__ O,
                const int* __restrict__ aidx, const int* __restrict__ bidx,
                const int* __restrict__ rlen, const int* __restrict__ cln,
                float* __restrict__ imp_c, float* __restrict__ imp_p_part, int Mfull)
{
    constexpr int MB = 64;
    constexpr int KI = NN / 64;          // kcol tiles per wave (4 waves along kcol)
    constexpr int NCH = NN / 32;         // PV k-chunks
    constexpr int XM = (NN / 4 > 32) ? 7 : 3;
    constexpr int CB = NN / 64;          // K staging insts

    __shared__ __align__(16) unsigned short As[2][MB * 32];
    __shared__ __align__(16) unsigned short BVs[2][8192];   // K tiles, then V chunks
    __shared__ __align__(16) unsigned short Ps[MB * NN];
    __shared__ float red0[MB][5];
    __shared__ float red1[MB][5];

    const int t = threadIdx.x;
    const int wid = t >> 6, l = t & 63, g = l >> 4, lr = l & 15;
    const int rbase = blockIdx.x * MB;
    const int bz = blockIdx.y;
    const int rl = rlen[bz], cl_ = cln[bz];

    // hoisted swizzle-folded row pointers for QK staging
    const unsigned short* apr;
    const unsigned short* bpr[CB];
    {
        int r = t >> 2, s = t & 3;
        apr = Qt + (size_t)aidx[bz * Mfull + rbase + r] * 768 + ((s ^ (r & 3)) << 3);
    }
#pragma unroll
    for (int p = 0; p < CB; ++p) {
        int i = p * 256 + t, c = i >> 2, s = i & 3;
        bpr[p] = Kt + (size_t)bidx[bz * NN + c] * 768 + ((s ^ (c & 3)) << 3);
    }

    f32x4 acc[KI][4];
#pragma unroll
    for (int ki = 0; ki < KI; ++ki)
#pragma unroll
        for (int qi = 0; qi < 4; ++qi) acc[ki][qi] = (f32x4){0.f, 0.f, 0.f, 0.f};

    auto stageQK = [&](int buf, int k0) {
        gld_lds16(apr + k0, &As[buf][t * 8]);
#pragma unroll
        for (int p = 0; p < CB; ++p)
            gld_lds16(bpr[p] + k0, &BVs[buf][(p * 256 + t) * 8]);
    };

    stageQK(0, 0);
    __syncthreads();
#pragma unroll 2
    for (int it = 0; it < 8; ++it) {
        const int cur = it & 1;
        if (it < 7) stageQK(cur ^ 1, (it + 1) * 32);
        short8 af[4], bf[KI];
#pragma unroll
        for (int qi = 0; qi < 4; ++qi) {
            int r = qi * 16 + lr;
            af[qi] = *(const short8*)&As[cur][r * 32 + ((g ^ (r & 3)) << 3)];
        }
#pragma unroll
        for (int ki = 0; ki < KI; ++ki) {
            int c = wid * (NN / 4) + ki * 16 + lr;
            bf[ki] = *(const short8*)&BVs[cur][c * 32 + ((g ^ (c & 3)) << 3)];
        }
#pragma unroll
        for (int ki = 0; ki < KI; ++ki)
#pragma unroll
            for (int qi = 0; qi < 4; ++qi)
                acc[ki][qi] = __builtin_amdgcn_mfma_f32_16x16x32_bf16(bf[ki], af[qi], acc[ki][qi], 0, 0, 0);
        if (it < 7) __syncthreads();
    }

    // issue V chunk-0 gathers now; they fly under the softmax
    const int va = t & 15, vcb = (t >> 4) * 16;
    ushort8 v0a, v0b, v1a, v1b;
    {
        const unsigned short* q0 = Vt + (size_t)bidx[bz * NN + 2 * va] * 768 + vcb;
        const unsigned short* q1 = Vt + (size_t)bidx[bz * NN + 2 * va + 1] * 768 + vcb;
        v0a = *(const ushort8*)q0; v0b = *(const ushort8*)(q0 + 8);
        v1a = *(const ushort8*)q1; v1b = *(const ushort8*)(q1 + 8);
    }
    auto writeV = [&](int buf) {
        int gg = va >> 2, kl = (2 * va) & 7;
#pragma unroll
        for (int e = 0; e < 8; ++e) {
            int c = vcb + e;
            *(unsigned*)&BVs[buf][c * 32 + ((gg ^ (c & 3)) << 3) + kl] =
                (unsigned)(unsigned short)v0a[e] | ((unsigned)(unsigned short)v1a[e] << 16);
        }
#pragma unroll
        for (int e = 0; e < 8; ++e) {
            int c = vcb + 8 + e;
            *(unsigned*)&BVs[buf][c * 32 + ((gg ^ (c & 3)) << 3) + kl] =
                (unsigned)(unsigned short)v0b[e] | ((unsigned)(unsigned short)v1b[e] << 16);
        }
    };

    // ---- mask + scale ----
#pragma unroll
    for (int ki = 0; ki < KI; ++ki)
#pragma unroll
        for (int qi = 0; qi < 4; ++qi)
#pragma unroll
            for (int q = 0; q < 4; ++q) {
                int kcol = wid * (NN / 4) + ki * 16 + g * 4 + q;
                int qrow = rbase + qi * 16 + lr;
                acc[ki][qi][q] = (qrow < rl && kcol < cl_) ? acc[ki][qi][q] * 0.0625f : -1e9f;
            }

    // ---- row max: in-lane (ki,q) + g-shuffles + 4-wide LDS ----
    float mx[4], inv[4];
#pragma unroll
    for (int qi = 0; qi < 4; ++qi) {
        float m = -1e30f;
#pragma unroll
        for (int ki = 0; ki < KI; ++ki)
#pragma unroll
            for (int q = 0; q < 4; ++q) m = fmaxf(m, acc[ki][qi][q]);
        m = fmaxf(m, __shfl_xor(m, 16));
        m = fmaxf(m, __shfl_xor(m, 32));
        mx[qi] = m;
    }
    if (g == 0)
#pragma unroll
        for (int qi = 0; qi < 4; ++qi) red0[qi * 16 + lr][wid] = mx[qi];
    __syncthreads();   // B1: red0 visible; all QK BVs reads complete
#pragma unroll
    for (int qi = 0; qi < 4; ++qi) {
        int row = qi * 16 + lr;
        mx[qi] = fmaxf(fmaxf(red0[row][0], red0[row][1]), fmaxf(red0[row][2], red0[row][3]));
    }

    // ---- exp + row sum ----
#pragma unroll
    for (int qi = 0; qi < 4; ++qi) {
        float s = 0.f;
#pragma unroll
        for (int ki = 0; ki < KI; ++ki)
#pragma unroll
            for (int q = 0; q < 4; ++q) {
                float e = exp2f((acc[ki][qi][q] - mx[qi]) * L2E);
                acc[ki][qi][q] = e;
                s += e;
            }
        s += __shfl_xor(s, 16);
        s += __shfl_xor(s, 32);
        mx[qi] = s;   // reuse as sum
    }
    if (g == 0)
#pragma unroll
        for (int qi = 0; qi < 4; ++qi) red1[qi * 16 + lr][wid] = mx[qi];
    writeV(0);         // V chunk 0 -> BVs[0] (safe: post-B1)
    __syncthreads();   // B2: red1 visible
#pragma unroll
    for (int qi = 0; qi < 4; ++qi) {
        int row = qi * 16 + lr;
        inv[qi] = 1.f / (red1[row][0] + red1[row][1] + red1[row][2] + red1[row][3]);
    }

    if constexpr (IMP) {
        if (wid == 0 && g == 0)
#pragma unroll
            for (int qi = 0; qi < 4; ++qi)
                imp_c[bz * Mfull + rbase + qi * 16 + lr] = inv[qi];
#pragma unroll
        for (int ki = 0; ki < KI; ++ki)
#pragma unroll
            for (int q = 0; q < 4; ++q) {
                float m = -1e30f;
#pragma unroll
                for (int qi = 0; qi < 4; ++qi) {
                    bool vr = (rbase + qi * 16 + lr) < rl;
                    m = fmaxf(m, vr ? acc[ki][qi][q] * inv[qi] : -1e30f);
                }
#pragma unroll
                for (int o = 1; o < 16; o <<= 1) m = fmaxf(m, __shfl_xor(m, o));
                if (lr == 0) {
                    int kcol = wid * (NN / 4) + ki * 16 + g * 4 + q;
                    imp_p_part[((size_t)blockIdx.x * gridDim.y + bz) * NN + kcol] = m;
                }
            }
    }

    // ---- normalize + pack P into LDS (8B swizzled writes) ----
#pragma unroll
    for (int ki = 0; ki < KI; ++ki)
#pragma unroll
        for (int qi = 0; qi < 4; ++qi) {
            int row = qi * 16 + lr;
            int slot = (wid * (NN / 4) + ki * 16 + g * 4) >> 2;
            int slotp = slot ^ ((lr & XM) << 3);
            ushort4v pk;
            pk.x = f2b(acc[ki][qi][0] * inv[qi]);
            pk.y = f2b(acc[ki][qi][1] * inv[qi]);
            pk.z = f2b(acc[ki][qi][2] * inv[qi]);
            pk.w = f2b(acc[ki][qi][3] * inv[qi]);
            *(ushort4v*)&Ps[row * NN + slotp * 4] = pk;
        }
    __syncthreads();   // B3: Ps + V chunk 0 visible

    // ---- PV: O[64][256] = P @ V, swapped (A=V^T frag, B=P frag) ----
    f32x4 acc2[4][4];
#pragma unroll
    for (int di = 0; di < 4; ++di)
#pragma unroll
        for (int qi = 0; qi < 4; ++qi) acc2[di][qi] = (f32x4){0.f, 0.f, 0.f, 0.f};

#pragma unroll 2
    for (int ch = 0; ch < NCH; ++ch) {
        const int cur = ch & 1;
        if (ch + 1 < NCH) {   // issue next V gathers early
            const unsigned short* q0 = Vt + (size_t)bidx[bz * NN + (ch + 1) * 32 + 2 * va] * 768 + vcb;
            const unsigned short* q1 = Vt + (size_t)bidx[bz * NN + (ch + 1) * 32 + 2 * va + 1] * 768 + vcb;
            v0a = *(const ushort8*)q0; v0b = *(const ushort8*)(q0 + 8);
            v1a = *(const ushort8*)q1; v1b = *(const ushort8*)(q1 + 8);
        }
        short8 pf[4], vf[4];
#pragma unroll
        for (int qi = 0; qi < 4; ++qi) {
            int row = qi * 16 + lr;
            int slotr = (ch * 8 + 2 * g) ^ ((lr & XM) << 3);
            pf[qi] = *(const short8*)&Ps[row * NN + slotr * 4];
        }
#pragma unroll
        for (int di = 0; di < 4; ++di) {
            int c = wid * 64 + di * 16 + lr;
            vf[di] = *(const short8*)&BVs[cur][c * 32 + ((g ^ (c & 3)) << 3)];
        }
#pragma unroll
        for (int di = 0; di < 4; ++di)
#pragma unroll
            for (int qi = 0; qi < 4; ++qi)
                acc2[di][qi] = __builtin_amdgcn_mfma_f32_16x16x32_bf16(vf[di], pf[qi], acc2[di][qi], 0, 0, 0);
        if (ch + 1 < NCH) {
            writeV(cur ^ 1);
            __syncthreads();
        }
    }

    // ---- packed fused-output stores (4 consecutive dims per lane) ----
#pragma unroll
    for (int di = 0; di < 4; ++di)
#pragma unroll
        for (int qi = 0; qi < 4; ++qi) {
            int qrow = qi * 16 + lr;
            int dim = wid * 64 + di * 16 + g * 4;
            ushort4v pk;
            pk.x = f2b(acc2[di][qi][0]);
            pk.y = f2b(acc2[di][qi][1]);
            pk.z = f2b(acc2[di][qi][2]);
            pk.w = f2b(acc2[di][qi][3]);
            *(ushort4v*)&O[((size_t)bz * Mfull + rbase + qrow) * 256 + dim] = pk;
        }
}

__device__ __forceinline__ float br_max(float v, float* red)
{
#pragma unroll
    for (int o = 32; o; o >>= 1) v = fmaxf(v, __shfl_xor(v, o));
    __syncthreads();
    if ((threadIdx.x & 63) == 0) red[threadIdx.x >> 6] = v;
    __syncthreads();
    return fmaxf(fmaxf(red[0], red[1]), fmaxf(red[2], red[3]));
}

__device__ __forceinline__ float br_sum(float v, float* red)
{
#pragma unroll
    for (int o = 32; o; o >>= 1) v += __shfl_xor(v, o);
    __syncthreads();
    if ((threadIdx.x & 63) == 0) red[threadIdx.x >> 6] = v;
    __syncthreads();
    return red[0] + red[1] + red[2] + red[3];
}

__global__ __launch_bounds__(256)
void pool_kernel(const unsigned short* __restrict__ cg, const unsigned short* __restrict__ pg,
                 const float* __restrict__ imp_c, const float* __restrict__ imp_p_part,
                 const int* __restrict__ clens, const int* __restrict__ plens,
                 float* __restrict__ out)
{
    int b = blockIdx.x, t = threadIdx.x;
    __shared__ float w[256];
    __shared__ float red[4];
    int cl = clens[b], pl = plens[b];

    float x = (t < 128 && t < cl) ? imp_c[b * MC + t] : -1e30f;
    float mx = br_max(x, red);
    float e = (t < 128) ? exp2f((x - mx) * L2E) : 0.f;
    float s = br_sum(e, red);
    if (t < 128) w[t] = e / s;
    __syncthreads();

    float hv = 0.f;
    for (int n = 0; n < MC; ++n)
        hv += w[n] * b2f(cg[((size_t)b * MC + n) * 256 + t]);
    __syncthreads();

    float x2 = (t < pl) ? fmaxf(imp_p_part[(size_t)b * MP + t],
                                imp_p_part[(size_t)(NB + b) * MP + t]) : -1e30f;
    float mx2 = br_max(x2, red);
    float e2 = exp2f((x2 - mx2) * L2E);
    float s2 = br_sum(e2, red);
    w[t] = e2 / s2;
    __syncthreads();

    float dv = 0.f;
    for (int m = 0; m < MP; ++m)
        dv += w[m] * b2f(pg[((size_t)b * MP + m) * 256 + t]);

    float logit = br_sum(hv * dv, red);
    if (t == 0) out[b] = 1.f / (1.f + expf(-logit));
}

// ---------------------------------------------------------------------------
extern "C" void kernel_launch(void* const* d_in, const int* in_sizes, int n_in,
                              void* d_out, int out_size, void* d_ws, size_t ws_size,
                              hipStream_t stream)
{
    const float* comp_emb = (const float*)d_in[0];
    const float* prot_emb = (const float*)d_in[1];
    const int* comp_idx  = (const int*)d_in[18];
    const int* prot_idx  = (const int*)d_in[19];
    const int* comp_lens = (const int*)d_in[20];
    const int* prot_lens = (const int*)d_in[21];
    float* out = (float*)d_out;

    const int N_C = in_sizes[0] / 256;
    const int N_P = in_sizes[1] / 256;
    const size_t NTc = (size_t)N_C * 256;
    const size_t NTp = (size_t)N_P * 256;

    // ---- workspace layout (bf16 elems) ----
    unsigned short* comp_bf = (unsigned short*)d_ws;
    unsigned short* prot_bf = comp_bf + NTc;
    unsigned short* Wcat    = prot_bf + NTp;                 // [2048][256]
    float* bias_cat         = (float*)(Wcat + 2048 * 256);   // [2048]
    unsigned short* tabC    = (unsigned short*)(bias_cat + 2048);  // [N_C][768] q|k|v
    unsigned short* tabP    = tabC + (size_t)N_C * 768;            // [N_P][768] q|k|v
    unsigned short* cfused  = tabP + (size_t)N_P * 768;      // [NB][128][256]
    unsigned short* pfused  = cfused + (size_t)NB * MC * 256; // [NB][256][256]
    float* imp_c      = (float*)(pfused + (size_t)NB * MP * 256);
    float* imp_p_part = imp_c + NB * MC;                     // [2][NB][256]

    // ---- conversions ----
    cvt_f32_bf16<<<dim3(2048), 256, 0, stream>>>(comp_emb, comp_bf, (int)(NTc / 4));
    cvt_f32_bf16<<<dim3(2048), 256, 0, stream>>>(prot_emb, prot_bf, (int)(NTp / 4));
    cvt_weights8<<<dim3(64, 8), 256, 0, stream>>>(
        (const float*)d_in[2], (const float*)d_in[4], (const float*)d_in[6], (const float*)d_in[14],
        (const float*)d_in[8], (const float*)d_in[10], (const float*)d_in[12], (const float*)d_in[16],
        (const float*)d_in[3], (const float*)d_in[5], (const float*)d_in[7], (const float*)d_in[15],
        (const float*)d_in[9], (const float*)d_in[11], (const float*)d_in[13], (const float*)d_in[17],
        Wcat, bias_cat);

    const int gpc = (N_C + 127) / 128, gpp = (N_P + 127) / 128;

    // ---- fused qkv projections (one per side) ----
    mfma_gemm<0><<<dim3(gpc, 6, 1), 256, 0, stream>>>(comp_bf, Wcat, tabC, bias_cat,
        N_C, 768, 256, 256);
    mfma_gemm<0><<<dim3(gpp, 6, 1), 256, 0, stream>>>(prot_bf, Wcat + 1024 * 256, tabP, bias_cat + 1024,
        N_P, 768, 256, 256);

    // ---- mega-fused attention, both directions ----
    attn_fused<256, true><<<dim3(2, NB), 256, 0, stream>>>(
        tabC, tabP + 256, tabP + 512, cfused,
        comp_idx, prot_idx, comp_lens, prot_lens, imp_c, imp_p_part, MC);
    attn_fused<128, false><<<dim3(4, NB), 256, 0, stream>>>(
        tabP, tabC + 256, tabC + 512, pfused,
        prot_idx, comp_idx, prot_lens, comp_lens, nullptr, nullptr, MP);

    // ---- sigmoid gating (in place) ----
    mfma_gemm<3><<<dim3((NB * MC) / 64, 1, 1), 256, 0, stream>>>(cfused, Wcat + 768 * 256, cfused, bias_cat + 768,
        NB * MC, 256, 256, 256);
    mfma_gemm<3><<<dim3((NB * MP) / 64, 1, 1), 256, 0, stream>>>(pfused, Wcat + 1792 * 256, pfused, bias_cat + 1792,
        NB * MP, 256, 256, 256);

    // ---- pooling + logit ----
    pool_kernel<<<dim3(NB), 256, 0, stream>>>(cfused, pfused, imp_c, imp_p_part, comp_lens, prot_lens, out);
}

// Round 8
// 198.965 us; speedup vs baseline: 1.0224x; 1.0070x over previous
//
#include <hip/hip_runtime.h>
#include <cstdint>

typedef __attribute__((ext_vector_type(8))) short short8;
typedef __attribute__((ext_vector_type(8))) unsigned short ushort8;
typedef __attribute__((ext_vector_type(4))) unsigned short ushort4v;
typedef __attribute__((ext_vector_type(4))) float f32x4;

constexpr int NB = 256, MC = 128, MP = 256;
constexpr float L2E = 1.442695041f;

__device__ __forceinline__ float b2f(unsigned short h) { return __uint_as_float(((unsigned)h) << 16); }
__device__ __forceinline__ unsigned short f2b(float f) {
    unsigned u = __float_as_uint(f);
    u += 0x7fffu + ((u >> 16) & 1u);
    return (unsigned short)(u >> 16);
}
__device__ __forceinline__ float sigmoid_f(float x) {
    return __builtin_amdgcn_rcpf(1.f + exp2f(-L2E * x));
}
__device__ __forceinline__ void gld_lds16(const unsigned short* g, unsigned short* l) {
    __builtin_amdgcn_global_load_lds((const __attribute__((address_space(1))) void*)g,
                                     (__attribute__((address_space(3))) void*)l, 16, 0, 0);
}

__global__ __launch_bounds__(256)
void cvt_f32_bf16(const float* __restrict__ in, unsigned short* __restrict__ out, int n4) {
    int i = blockIdx.x * 256 + threadIdx.x;
    int stride = gridDim.x * 256;
    for (; i < n4; i += stride) {
        float4 v = ((const float4*)in)[i];
        ushort4v o;
        o.x = f2b(v.x); o.y = f2b(v.y); o.z = f2b(v.z); o.w = f2b(v.w);
        ((ushort4v*)out)[i] = o;
    }
}

// 8 weights -> Wcat [2048][256] bf16 + bias_cat[2048] f32.
// Row-block order: q_c,k_c,v_c,g_c,q_p,k_p,v_p,g_p (qkv contiguous per side).
__global__ __launch_bounds__(256)
void cvt_weights8(const float* w0, const float* w1, const float* w2, const float* w3,
                  const float* w4, const float* w5, const float* w6, const float* w7,
                  const float* b0, const float* b1, const float* b2, const float* b3,
                  const float* b4, const float* b5, const float* b6, const float* b7,
                  unsigned short* __restrict__ Wcat, float* __restrict__ bias_cat)
{
    const float* wsel[8] = {w0, w1, w2, w3, w4, w5, w6, w7};
    const float* bsel[8] = {b0, b1, b2, b3, b4, b5, b6, b7};
    int j = blockIdx.y;
    int i = blockIdx.x * 256 + threadIdx.x;
    float4 v = ((const float4*)wsel[j])[i];
    ushort4v o;
    o.x = f2b(v.x); o.y = f2b(v.y); o.z = f2b(v.z); o.w = f2b(v.w);
    ((ushort4v*)(Wcat + (size_t)j * 65536))[i] = o;
    if (blockIdx.x == 0) bias_cat[j * 256 + threadIdx.x] = bsel[j][threadIdx.x];
}

// ---------------------------------------------------------------------------
// bf16 MFMA GEMM, double-buffered BK=32 (2-phase pipeline).  (modes 0 & 3)
// LDS: elem (row r,k) at short-index r*32 + ((k>>3 ^ (r&3))<<3) + (k&7);
// staged linearly from inverse-swizzled GLOBAL source (rule #21).
// MODE 0 proj : Y[gr,gc] = dot + bias[gc], C stride N (N=768 fused qkv)
// MODE 3 gate : C = C * sigmoid(dot + bias), in place (block owns full rows)
// ---------------------------------------------------------------------------
template<int MODE>
__global__ __launch_bounds__(256, 4)
void mfma_gemm(const unsigned short* __restrict__ A, const unsigned short* __restrict__ B,
               unsigned short* __restrict__ C, const float* __restrict__ bias,
               int M, int N, int K, int bstr)
{
    constexpr int BM = (MODE == 3) ? 64 : 128;
    constexpr int BN = (MODE == 3) ? 256 : 128;
    __shared__ __align__(16) unsigned short As[2][BM * 32];
    __shared__ __align__(16) unsigned short Bs[2][BN * 32];

    const int t = threadIdx.x;
    const int wid = t >> 6, l = t & 63, g = l >> 4, lr = l & 15;
    const int wrb = (MODE == 3) ? 0 : (wid >> 1) * 64;
    const int wcb = (MODE == 3) ? wid * 64 : (wid & 1) * 64;
    const int r0 = blockIdx.x * BM, c0 = blockIdx.y * BN;

    f32x4 acc[4][4];
#pragma unroll
    for (int mi = 0; mi < 4; ++mi)
#pragma unroll
        for (int ni = 0; ni < 4; ++ni) acc[mi][ni] = (f32x4){0.f, 0.f, 0.f, 0.f};

    auto stage = [&](int buf, int k0) {
        constexpr int CA = (BM * 4) / 256;
#pragma unroll
        for (int p = 0; p < CA; ++p) {
            int i = p * 256 + t;
            int r = i >> 2, s = i & 3;
            const unsigned short* ap;
            if constexpr (MODE == 0) { int gr = r0 + r; if (gr >= M) gr = M - 1; ap = A + (size_t)gr * 256; }
            else { ap = A + (size_t)(r0 + r) * 256; }
            gld_lds16(ap + k0 + ((s ^ (r & 3)) << 3), &As[buf][i * 8]);
        }
        constexpr int CB = (BN * 4) / 256;
#pragma unroll
        for (int p = 0; p < CB; ++p) {
            int i = p * 256 + t;
            int c = i >> 2, s = i & 3;
            const unsigned short* bp = B + (size_t)(c0 + c) * bstr;
            gld_lds16(bp + k0 + ((s ^ (c & 3)) << 3), &Bs[buf][i * 8]);
        }
    };

    stage(0, 0);
    __syncthreads();
    const int NT_ = K >> 5;
    for (int it = 0; it < NT_; ++it) {
        const int cur = it & 1;
        if (it + 1 < NT_) stage(cur ^ 1, (it + 1) << 5);
        short8 af[4], bfr[4];
#pragma unroll
        for (int mi = 0; mi < 4; ++mi) {
            int r = wrb + mi * 16 + lr;
            af[mi] = *(const short8*)&As[cur][r * 32 + ((g ^ (r & 3)) << 3)];
        }
#pragma unroll
        for (int ni = 0; ni < 4; ++ni) {
            int c = wcb + ni * 16 + lr;
            bfr[ni] = *(const short8*)&Bs[cur][c * 32 + ((g ^ (c & 3)) << 3)];
        }
#pragma unroll
        for (int mi = 0; mi < 4; ++mi)
#pragma unroll
            for (int ni = 0; ni < 4; ++ni)
                acc[mi][ni] = __builtin_amdgcn_mfma_f32_16x16x32_bf16(af[mi], bfr[ni], acc[mi][ni], 0, 0, 0);
        if (it + 1 < NT_) __syncthreads();
    }

#pragma unroll
    for (int mi = 0; mi < 4; ++mi) {
#pragma unroll
        for (int ni = 0; ni < 4; ++ni) {
#pragma unroll
            for (int q = 0; q < 4; ++q) {
                int gr = r0 + wrb + mi * 16 + g * 4 + q;
                int gc = c0 + wcb + ni * 16 + lr;
                float v = acc[mi][ni][q];
                if constexpr (MODE == 0) {
                    if (gr < M) C[(size_t)gr * N + gc] = f2b(v + bias[gc]);
                } else {
                    size_t o = (size_t)gr * 256 + gc;
                    C[o] = f2b(b2f(C[o]) * sigmoid_f(v + bias[gc]));
                }
            }
        }
    }
}

// ---------------------------------------------------------------------------
// Mega-fused attention v2 — wave-private, barrier-free pipelines.
// Key property: wave wid only ever READS K rows / V dims wid*64..+63 (cp;
// wid*32 kcols for pc), and writes the same region -> K-staging (gld_lds)
// and V-staging (reg->ds_write) are wave-private. Q fragments load straight
// to registers. So the QK loop and PV loop need NO barriers: each wave
// self-paces with counted `s_waitcnt vmcnt(KI+4)` (T4) between sched_barrier
// walls (rule #18). Only 3 barriers remain (2 softmax reductions + Ps handoff).
// Ps swizzle: slot ^ ((row&7)<<1) — bank = 2*slot mod 32 depends on slot bits
// 0..3, so XOR must mix low bits (fixes R7's 2.5M conflicts). b128 reads stay
// pair-contiguous (XOR even).
// ---------------------------------------------------------------------------
template<int NN, bool IMP>
__global__ __launch_bounds__(256, 2)
void attn_fused(const unsigned short* __restrict__ Qt, const unsigned short* __restrict__ Kt,
                const unsigned short* __restrict__ Vt, unsigned short* __restrict__ O,
                const int* __restrict__ aidx, const int* __restrict__ bidx,
                const int* __restrict__ rlen, const int* __restrict__ cln,
                float* __restrict__ imp_c, float* __restrict__ imp_p_part, int Mfull)
{
    constexpr int MB = 64;
    constexpr int KI = NN / 64;          // kcol 16-tiles per wave; K-stage instrs per tile
    constexpr int NCH = NN / 32;         // PV chunks

    __shared__ __align__(16) unsigned short BVs[2][8192];   // K (wave-private rows) then V chunks
    __shared__ __align__(16) unsigned short Ps[MB * NN];
    __shared__ float red0[MB][5];
    __shared__ float red1[MB][5];

    const int t = threadIdx.x;
    const int wid = t >> 6, l = t & 63, g = l >> 4, lr = l & 15;
    const int rbase = blockIdx.x * MB;
    const int bz = blockIdx.y;
    const int rl = rlen[bz], cl_ = cln[bz];

    // ---- hoisted per-lane pointers ----
    // K: wave-private rows wid*(NN/4) + p*16 + (l>>2), 16B chunk s=l&3 (src-swizzled)
    const unsigned short* kp[KI];
#pragma unroll
    for (int p = 0; p < KI; ++p) {
        int c = wid * (NN / 4) + p * 16 + (l >> 2);
        kp[p] = Kt + (size_t)bidx[bz * NN + c] * 768 + (((l & 3) ^ (c & 3)) << 3);
    }
    // Q: direct-to-register fragments, row qi*16+lr, chunk g
    const unsigned short* qp[4];
#pragma unroll
    for (int qi = 0; qi < 4; ++qi)
        qp[qi] = Qt + (size_t)aidx[bz * Mfull + rbase + qi * 16 + lr] * 768 + g * 8;

    auto stageK = [&](int buf, int k0) {
#pragma unroll
        for (int p = 0; p < KI; ++p)
            gld_lds16(kp[p] + k0, &BVs[buf][(wid * (NN / 4) + p * 16) * 32 + l * 8]);
    };

    f32x4 acc[KI][4];
#pragma unroll
    for (int ki = 0; ki < KI; ++ki)
#pragma unroll
        for (int qi = 0; qi < 4; ++qi) acc[ki][qi] = (f32x4){0.f, 0.f, 0.f, 0.f};

    short8 afb[2][4];
    stageK(0, 0);
#pragma unroll
    for (int qi = 0; qi < 4; ++qi) afb[0][qi] = *(const short8*)(qp[qi]);

    // ---- QK loop: barrier-free, counted-vmcnt self-paced (T4) ----
#pragma unroll
    for (int it = 0; it < 8; ++it) {
        const int cur = it & 1;
        if (it < 7) {
            stageK(cur ^ 1, (it + 1) * 32);
#pragma unroll
            for (int qi = 0; qi < 4; ++qi)
                afb[cur ^ 1][qi] = *(const short8*)(qp[qi] + (it + 1) * 32);
            __builtin_amdgcn_sched_barrier(0);
            if constexpr (NN == 256) asm volatile("s_waitcnt vmcnt(8)" ::: "memory");
            else                     asm volatile("s_waitcnt vmcnt(6)" ::: "memory");
            __builtin_amdgcn_sched_barrier(0);
        } else {
            asm volatile("s_waitcnt vmcnt(0)" ::: "memory");
            __builtin_amdgcn_sched_barrier(0);
        }
        short8 bf[KI];
#pragma unroll
        for (int ki = 0; ki < KI; ++ki) {
            int c = wid * (NN / 4) + ki * 16 + lr;
            bf[ki] = *(const short8*)&BVs[cur][c * 32 + ((g ^ (c & 3)) << 3)];
        }
#pragma unroll
        for (int ki = 0; ki < KI; ++ki)
#pragma unroll
            for (int qi = 0; qi < 4; ++qi)
                acc[ki][qi] = __builtin_amdgcn_mfma_f32_16x16x32_bf16(bf[ki], afb[cur][qi], acc[ki][qi], 0, 0, 0);
    }

    // ---- issue V chunk-0 gathers (fly under softmax); wave-private dims ----
    const int va = l & 15, vcb = wid * 64 + (l >> 4) * 16;
    ushort8 v0a, v0b, v1a, v1b;
    {
        const unsigned short* q0 = Vt + (size_t)bidx[bz * NN + 2 * va] * 768 + vcb;
        const unsigned short* q1 = Vt + (size_t)bidx[bz * NN + 2 * va + 1] * 768 + vcb;
        v0a = *(const ushort8*)q0; v0b = *(const ushort8*)(q0 + 8);
        v1a = *(const ushort8*)q1; v1b = *(const ushort8*)(q1 + 8);
    }
    auto writeV = [&](int buf) {
        int gg = va >> 2, kl = (2 * va) & 7;
#pragma unroll
        for (int e = 0; e < 8; ++e) {
            int c = vcb + e;
            *(unsigned*)&BVs[buf][c * 32 + ((gg ^ (c & 3)) << 3) + kl] =
                (unsigned)(unsigned short)v0a[e] | ((unsigned)(unsigned short)v1a[e] << 16);
        }
#pragma unroll
        for (int e = 0; e < 8; ++e) {
            int c = vcb + 8 + e;
            *(unsigned*)&BVs[buf][c * 32 + ((gg ^ (c & 3)) << 3) + kl] =
                (unsigned)(unsigned short)v0b[e] | ((unsigned)(unsigned short)v1b[e] << 16);
        }
    };

    // ---- mask + scale ----
#pragma unroll
    for (int ki = 0; ki < KI; ++ki)
#pragma unroll
        for (int qi = 0; qi < 4; ++qi)
#pragma unroll
            for (int q = 0; q < 4; ++q) {
                int kcol = wid * (NN / 4) + ki * 16 + g * 4 + q;
                int qrow = rbase + qi * 16 + lr;
                acc[ki][qi][q] = (qrow < rl && kcol < cl_) ? acc[ki][qi][q] * 0.0625f : -1e9f;
            }

    // ---- row max ----
    float mx[4], inv[4];
#pragma unroll
    for (int qi = 0; qi < 4; ++qi) {
        float m = -1e30f;
#pragma unroll
        for (int ki = 0; ki < KI; ++ki)
#pragma unroll
            for (int q = 0; q < 4; ++q) m = fmaxf(m, acc[ki][qi][q]);
        m = fmaxf(m, __shfl_xor(m, 16));
        m = fmaxf(m, __shfl_xor(m, 32));
        mx[qi] = m;
    }
    if (g == 0)
#pragma unroll
        for (int qi = 0; qi < 4; ++qi) red0[qi * 16 + lr][wid] = mx[qi];
    __syncthreads();   // B1
#pragma unroll
    for (int qi = 0; qi < 4; ++qi) {
        int row = qi * 16 + lr;
        mx[qi] = fmaxf(fmaxf(red0[row][0], red0[row][1]), fmaxf(red0[row][2], red0[row][3]));
    }

    // ---- exp + row sum ----
#pragma unroll
    for (int qi = 0; qi < 4; ++qi) {
        float s = 0.f;
#pragma unroll
        for (int ki = 0; ki < KI; ++ki)
#pragma unroll
            for (int q = 0; q < 4; ++q) {
                float e = exp2f((acc[ki][qi][q] - mx[qi]) * L2E);
                acc[ki][qi][q] = e;
                s += e;
            }
        s += __shfl_xor(s, 16);
        s += __shfl_xor(s, 32);
        mx[qi] = s;
    }
    if (g == 0)
#pragma unroll
        for (int qi = 0; qi < 4; ++qi) red1[qi * 16 + lr][wid] = mx[qi];
    writeV(0);         // wave-private V chunk 0 -> BVs[0]
    __syncthreads();   // B2
#pragma unroll
    for (int qi = 0; qi < 4; ++qi) {
        int row = qi * 16 + lr;
        inv[qi] = 1.f / (red1[row][0] + red1[row][1] + red1[row][2] + red1[row][3]);
    }

    if constexpr (IMP) {
        if (wid == 0 && g == 0)
#pragma unroll
            for (int qi = 0; qi < 4; ++qi)
                imp_c[bz * Mfull + rbase + qi * 16 + lr] = inv[qi];
#pragma unroll
        for (int ki = 0; ki < KI; ++ki)
#pragma unroll
            for (int q = 0; q < 4; ++q) {
                float m = -1e30f;
#pragma unroll
                for (int qi = 0; qi < 4; ++qi) {
                    bool vr = (rbase + qi * 16 + lr) < rl;
                    m = fmaxf(m, vr ? acc[ki][qi][q] * inv[qi] : -1e30f);
                }
#pragma unroll
                for (int o = 1; o < 16; o <<= 1) m = fmaxf(m, __shfl_xor(m, o));
                if (lr == 0) {
                    int kcol = wid * (NN / 4) + ki * 16 + g * 4 + q;
                    imp_p_part[((size_t)blockIdx.x * gridDim.y + bz) * NN + kcol] = m;
                }
            }
    }

    // ---- normalize + pack P into LDS (8B writes, fixed swizzle) ----
#pragma unroll
    for (int ki = 0; ki < KI; ++ki)
#pragma unroll
        for (int qi = 0; qi < 4; ++qi) {
            int row = qi * 16 + lr;
            int slot = wid * (NN / 16) + ki * 4 + g;
            int slotp = slot ^ ((lr & 7) << 1);
            ushort4v pk;
            pk.x = f2b(acc[ki][qi][0] * inv[qi]);
            pk.y = f2b(acc[ki][qi][1] * inv[qi]);
            pk.z = f2b(acc[ki][qi][2] * inv[qi]);
            pk.w = f2b(acc[ki][qi][3] * inv[qi]);
            *(ushort4v*)&Ps[row * NN + slotp * 4] = pk;
        }
    __syncthreads();   // B3: Ps handoff (the only cross-wave data)

    // ---- PV: barrier-free chunk loop (V staging wave-private) ----
    f32x4 acc2[4][4];
#pragma unroll
    for (int di = 0; di < 4; ++di)
#pragma unroll
        for (int qi = 0; qi < 4; ++qi) acc2[di][qi] = (f32x4){0.f, 0.f, 0.f, 0.f};

#pragma unroll 2
    for (int ch = 0; ch < NCH; ++ch) {
        const int cur = ch & 1;
        if (ch + 1 < NCH) {
            const unsigned short* q0 = Vt + (size_t)bidx[bz * NN + (ch + 1) * 32 + 2 * va] * 768 + vcb;
            const unsigned short* q1 = Vt + (size_t)bidx[bz * NN + (ch + 1) * 32 + 2 * va + 1] * 768 + vcb;
            v0a = *(const ushort8*)q0; v0b = *(const ushort8*)(q0 + 8);
            v1a = *(const ushort8*)q1; v1b = *(const ushort8*)(q1 + 8);
        }
        short8 pf[4], vf[4];
#pragma unroll
        for (int qi = 0; qi < 4; ++qi) {
            int row = qi * 16 + lr;
            int slotr = (ch * 8 + 2 * g) ^ ((lr & 7) << 1);
            pf[qi] = *(const short8*)&Ps[row * NN + slotr * 4];
        }
#pragma unroll
        for (int di = 0; di < 4; ++di) {
            int c = wid * 64 + di * 16 + lr;
            vf[di] = *(const short8*)&BVs[cur][c * 32 + ((g ^ (c & 3)) << 3)];
        }
#pragma unroll
        for (int di = 0; di < 4; ++di)
#pragma unroll
            for (int qi = 0; qi < 4; ++qi)
                acc2[di][qi] = __builtin_amdgcn_mfma_f32_16x16x32_bf16(vf[di], pf[qi], acc2[di][qi], 0, 0, 0);
        if (ch + 1 < NCH) writeV(cur ^ 1);
    }

    // ---- packed fused-output stores ----
#pragma unroll
    for (int di = 0; di < 4; ++di)
#pragma unroll
        for (int qi = 0; qi < 4; ++qi) {
            int qrow = qi * 16 + lr;
            int dim = wid * 64 + di * 16 + g * 4;
            ushort4v pk;
            pk.x = f2b(acc2[di][qi][0]);
            pk.y = f2b(acc2[di][qi][1]);
            pk.z = f2b(acc2[di][qi][2]);
            pk.w = f2b(acc2[di][qi][3]);
            *(ushort4v*)&O[((size_t)bz * Mfull + rbase + qrow) * 256 + dim] = pk;
        }
}

__device__ __forceinline__ float br_max(float v, float* red)
{
#pragma unroll
    for (int o = 32; o; o >>= 1) v = fmaxf(v, __shfl_xor(v, o));
    __syncthreads();
    if ((threadIdx.x & 63) == 0) red[threadIdx.x >> 6] = v;
    __syncthreads();
    return fmaxf(fmaxf(red[0], red[1]), fmaxf(red[2], red[3]));
}

__device__ __forceinline__ float br_sum(float v, float* red)
{
#pragma unroll
    for (int o = 32; o; o >>= 1) v += __shfl_xor(v, o);
    __syncthreads();
    if ((threadIdx.x & 63) == 0) red[threadIdx.x >> 6] = v;
    __syncthreads();
    return red[0] + red[1] + red[2] + red[3];
}

__global__ __launch_bounds__(256)
void pool_kernel(const unsigned short* __restrict__ cg, const unsigned short* __restrict__ pg,
                 const float* __restrict__ imp_c, const float* __restrict__ imp_p_part,
                 const int* __restrict__ clens, const int* __restrict__ plens,
                 float* __restrict__ out)
{
    int b = blockIdx.x, t = threadIdx.x;
    __shared__ float w[256];
    __shared__ float red[4];
    int cl = clens[b], pl = plens[b];

    float x = (t < 128 && t < cl) ? imp_c[b * MC + t] : -1e30f;
    float mx = br_max(x, red);
    float e = (t < 128) ? exp2f((x - mx) * L2E) : 0.f;
    float s = br_sum(e, red);
    if (t < 128) w[t] = e / s;
    __syncthreads();

    float hv = 0.f;
    for (int n = 0; n < MC; ++n)
        hv += w[n] * b2f(cg[((size_t)b * MC + n) * 256 + t]);
    __syncthreads();

    float x2 = (t < pl) ? fmaxf(imp_p_part[(size_t)b * MP + t],
                                imp_p_part[(size_t)(NB + b) * MP + t]) : -1e30f;
    float mx2 = br_max(x2, red);
    float e2 = exp2f((x2 - mx2) * L2E);
    float s2 = br_sum(e2, red);
    w[t] = e2 / s2;
    __syncthreads();

    float dv = 0.f;
    for (int m = 0; m < MP; ++m)
        dv += w[m] * b2f(pg[((size_t)b * MP + m) * 256 + t]);

    float logit = br_sum(hv * dv, red);
    if (t == 0) out[b] = 1.f / (1.f + expf(-logit));
}

// ---------------------------------------------------------------------------
extern "C" void kernel_launch(void* const* d_in, const int* in_sizes, int n_in,
                              void* d_out, int out_size, void* d_ws, size_t ws_size,
                              hipStream_t stream)
{
    const float* comp_emb = (const float*)d_in[0];
    const float* prot_emb = (const float*)d_in[1];
    const int* comp_idx  = (const int*)d_in[18];
    const int* prot_idx  = (const int*)d_in[19];
    const int* comp_lens = (const int*)d_in[20];
    const int* prot_lens = (const int*)d_in[21];
    float* out = (float*)d_out;

    const int N_C = in_sizes[0] / 256;
    const int N_P = in_sizes[1] / 256;
    const size_t NTc = (size_t)N_C * 256;
    const size_t NTp = (size_t)N_P * 256;

    // ---- workspace layout (bf16 elems) ----
    unsigned short* comp_bf = (unsigned short*)d_ws;
    unsigned short* prot_bf = comp_bf + NTc;
    unsigned short* Wcat    = prot_bf + NTp;                 // [2048][256]
    float* bias_cat         = (float*)(Wcat + 2048 * 256);   // [2048]
    unsigned short* tabC    = (unsigned short*)(bias_cat + 2048);  // [N_C][768] q|k|v
    unsigned short* tabP    = tabC + (size_t)N_C * 768;            // [N_P][768] q|k|v
    unsigned short* cfused  = tabP + (size_t)N_P * 768;      // [NB][128][256]
    unsigned short* pfused  = cfused + (size_t)NB * MC * 256; // [NB][256][256]
    float* imp_c      = (float*)(pfused + (size_t)NB * MP * 256);
    float* imp_p_part = imp_c + NB * MC;                     // [2][NB][256]

    // ---- conversions ----
    cvt_f32_bf16<<<dim3(2048), 256, 0, stream>>>(comp_emb, comp_bf, (int)(NTc / 4));
    cvt_f32_bf16<<<dim3(2048), 256, 0, stream>>>(prot_emb, prot_bf, (int)(NTp / 4));
    cvt_weights8<<<dim3(64, 8), 256, 0, stream>>>(
        (const float*)d_in[2], (const float*)d_in[4], (const float*)d_in[6], (const float*)d_in[14],
        (const float*)d_in[8], (const float*)d_in[10], (const float*)d_in[12], (const float*)d_in[16],
        (const float*)d_in[3], (const float*)d_in[5], (const float*)d_in[7], (const float*)d_in[15],
        (const float*)d_in[9], (const float*)d_in[11], (const float*)d_in[13], (const float*)d_in[17],
        Wcat, bias_cat);

    const int gpc = (N_C + 127) / 128, gpp = (N_P + 127) / 128;

    // ---- fused qkv projections (one per side) ----
    mfma_gemm<0><<<dim3(gpc, 6, 1), 256, 0, stream>>>(comp_bf, Wcat, tabC, bias_cat,
        N_C, 768, 256, 256);
    mfma_gemm<0><<<dim3(gpp, 6, 1), 256, 0, stream>>>(prot_bf, Wcat + 1024 * 256, tabP, bias_cat + 1024,
        N_P, 768, 256, 256);

    // ---- mega-fused attention, both directions ----
    attn_fused<256, true><<<dim3(2, NB), 256, 0, stream>>>(
        tabC, tabP + 256, tabP + 512, cfused,
        comp_idx, prot_idx, comp_lens, prot_lens, imp_c, imp_p_part, MC);
    attn_fused<128, false><<<dim3(4, NB), 256, 0, stream>>>(
        tabP, tabC + 256, tabC + 512, pfused,
        prot_idx, comp_idx, prot_lens, comp_lens, nullptr, nullptr, MP);

    // ---- sigmoid gating (in place) ----
    mfma_gemm<3><<<dim3((NB * MC) / 64, 1, 1), 256, 0, stream>>>(cfused, Wcat + 768 * 256, cfused, bias_cat + 768,
        NB * MC, 256, 256, 256);
    mfma_gemm<3><<<dim3((NB * MP) / 64, 1, 1), 256, 0, stream>>>(pfused, Wcat + 1792 * 256, pfused, bias_cat + 1792,
        NB * MP, 256, 256, 256);

    // ---- pooling + logit ----
    pool_kernel<<<dim3(NB), 256, 0, stream>>>(cfused, pfused, imp_c, imp_p_part, comp_lens, prot_lens, out);
}